// Round 7
// baseline (282.021 us; speedup 1.0000x reference)
//
#include <hip/hip_runtime.h>
#include <stdint.h>

// ---------------------------------------------------------------------------
// CausalSelfAttention: x[4,2048,1024] -> qkv -> flash attn -> proj
// Round 10: GEMM rebuilt as k_gemm2: 256x128 tile, 8 waves, acc[8][2],
// A dbuf (64K) + B single-buf (16K) = 80 KiB LDS -> 2 blocks/CU, 4 waves/SIMD
// (launch_bounds(512,4), 64 AGPR acc + ~60 VGPR <= 128 budget).
// Diagnosis: all prior GEMM variants pinned at ~26% MfmaUtil -- R6-style
// (1 blk/CU, 2 waves/SIMD) is LDS-read latency-chained; R0-style (deep TLP,
// 1KB/MFMA) was LDS-BW capped.  This design keeps intensity at 0.625 KB/MFMA
// AND doubles waves/SIMD with desynced dual blocks hiding each other's
// vmcnt/barrier drains (the mechanism that works in k_flash at 4 blk/CU).
// Flash (XCD-grouped R8) and transposes unchanged.
// ---------------------------------------------------------------------------

typedef __attribute__((ext_vector_type(8))) short short8;   // 8 bf16 (4 VGPRs)
typedef __attribute__((ext_vector_type(4))) float floatx4;  // MFMA C/D frag

#define AS1C(p) ((const __attribute__((address_space(1))) void*)(p))
#define AS3(p)  ((__attribute__((address_space(3))) void*)(p))
#define GL16(src, dst) __builtin_amdgcn_global_load_lds(AS1C(src), AS3(dst), 16, 0, 0)
#define BARRIER() do { asm volatile("" ::: "memory"); __builtin_amdgcn_s_barrier(); asm volatile("" ::: "memory"); } while (0)

__device__ __forceinline__ unsigned short f2bf(float f) {
  unsigned int u = __builtin_bit_cast(unsigned int, f);
  u = (u + 0x7fffu + ((u >> 16) & 1u)) >> 16;   // RNE
  return (unsigned short)u;
}
__device__ __forceinline__ unsigned short f2bf_trunc(float f) {
  return (unsigned short)(__builtin_bit_cast(unsigned int, f) >> 16);
}

// ---- fp32 -> bf16 elementwise (x4 vectorized) ----
__global__ void k_cvt(const float* __restrict__ in, unsigned short* __restrict__ out, int n4) {
  int i = blockIdx.x * blockDim.x + threadIdx.x;
  if (i < n4) {
    float4 v = ((const float4*)in)[i];
    ushort4 o;
    o.x = f2bf(v.x); o.y = f2bf(v.y); o.z = f2bf(v.z); o.w = f2bf(v.w);
    ((ushort4*)out)[i] = o;
  }
}

// ---- transpose fp32 [K][N] -> bf16 [N][K] (weights) ----
__global__ void k_tw(const float* __restrict__ in, unsigned short* __restrict__ out, int K, int N) {
  __shared__ float t[32][33];
  int n0 = blockIdx.x * 32, k0 = blockIdx.y * 32;
  int tx = threadIdx.x, ty = threadIdx.y;
#pragma unroll
  for (int i = 0; i < 4; i++)
    t[ty + 8 * i][tx] = in[(size_t)(k0 + ty + 8 * i) * N + n0 + tx];
  __syncthreads();
#pragma unroll
  for (int i = 0; i < 4; i++)
    out[(size_t)(n0 + ty + 8 * i) * K + k0 + tx] = f2bf(t[tx][ty + 8 * i]);
}

// ---- transpose V slice of qkv (bf16) -> VT[bh][d][t] ----
__global__ void k_tv(const unsigned short* __restrict__ qkv, unsigned short* __restrict__ vt) {
  __shared__ unsigned short t[32][33];
  int t0 = blockIdx.x * 32;         // time tile
  int d0 = blockIdx.y * 32;         // head-dim tile (0 or 32)
  int bh = blockIdx.z;              // 0..63
  int b = bh >> 4, h = bh & 15;
  int tx = threadIdx.x, ty = threadIdx.y;
#pragma unroll
  for (int i = 0; i < 4; i++)
    t[ty + 8 * i][tx] = qkv[(size_t)(b * 2048 + t0 + ty + 8 * i) * 3072 + 2048 + h * 64 + d0 + tx];
  __syncthreads();
#pragma unroll
  for (int i = 0; i < 4; i++)
    vt[(size_t)(bh * 64 + d0 + ty + 8 * i) * 2048 + t0 + tx] = t[tx][ty + 8 * i];
}

// ---------------------------------------------------------------------------
// 256x128-tile bf16 GEMM, C = A[M,K] @ Bt[N,K]^T + bias.  2 blocks/CU.
// 8 waves: wm=(wv>>2)*128, wn=(wv&3)*32 -> per-wave 128x32, acc[8][2].
// LDS: lA dbuf 64K + lB single 16K = 80K exactly (2 blocks per 160K CU).
// Per K-tile: issue A(t+1)->lA[(t+1)&1] at tile start (parity last read by
// tile t-1, consumed before its end barrier); read bf+af(m0-3); MFMA; BARRIER
// (all waves' bf reads consumed -> lB reusable); issue B(t+1)->lB; read
// af(m4-7); MFMA; vmcnt(0); BARRIER (t+1 staged data visible to all).
// ---------------------------------------------------------------------------
template <int OUT_F32>
__global__ __launch_bounds__(512, 4)
void k_gemm2(const unsigned short* __restrict__ A,
             const unsigned short* __restrict__ Bt,
             const float* __restrict__ bias,
             void* __restrict__ Cout, int M, int N, int K) {
  __shared__ unsigned short lA[2][256 * 64];   // 64 KiB
  __shared__ unsigned short lB[128 * 64];      // 16 KiB -> 80 KiB total
  int tid = threadIdx.x;
  int lane = tid & 63, wv = tid >> 6;          // 8 waves
  int lc = lane & 15, quad = lane >> 4;
  int sw = lc & 7;

  // T1: XCD-aware block swizzle (nwg % 8 == 0 for both launches)
  unsigned nbx = gridDim.x;
  unsigned nwg = nbx * gridDim.y;
  unsigned flat = blockIdx.y * nbx + blockIdx.x;
  unsigned cpx = nwg >> 3;
  unsigned tile = (flat & 7u) * cpx + (flat >> 3);
  int n0 = (int)(tile % nbx) * 128;
  int m0 = (int)(tile / nbx) * 256;

  int wm = (wv >> 2) * 128;   // 0,128
  int wn = (wv & 3) * 32;     // 0,32,64,96

  floatx4 acc[8][2];
#pragma unroll
  for (int i = 0; i < 8; i++)
#pragma unroll
    for (int j = 0; j < 2; j++) acc[i][j] = (floatx4){0.f, 0.f, 0.f, 0.f};

  // staging geometry: one gload issue = 512 thr x 16B = 8 KiB = 64 rows
  int srow = tid >> 3;                          // 0..63
  int scol = ((tid & 7) ^ (srow & 7)) * 8;      // inverse-swizzled source chunk
  const unsigned short* gA = A + (size_t)(m0 + srow) * K + scol;
  const unsigned short* gB = Bt + (size_t)(n0 + srow) * K + scol;

  int NT = K >> 6;

  // prologue: stage tile 0 (A->lA[0], B->lB); wait; barrier.
#pragma unroll
  for (int i = 0; i < 4; i++) GL16(gA + (size_t)(i * 64) * K, &lA[0][i * 4096 + wv * 512]);
#pragma unroll
  for (int i = 0; i < 2; i++) GL16(gB + (size_t)(i * 64) * K, &lB[i * 4096 + wv * 512]);
  asm volatile("s_waitcnt vmcnt(0)" ::: "memory");
  __builtin_amdgcn_s_barrier();
  asm volatile("" ::: "memory");

  for (int t = 0; t < NT; ++t) {
    const unsigned short* bufA = lA[t & 1];
    unsigned short* nA = lA[(t + 1) & 1];
    int k1 = (t + 1) << 6;
    bool st = (t + 1) < NT;

    // issue A(t+1) early: lA[(t+1)&1] was last read by tile t-1 (af m4-7),
    // consumed before t-1's end barrier -> safe.  Full-tile latency cover.
    if (st) {
#pragma unroll
      for (int i = 0; i < 4; i++)
        GL16(gA + (size_t)(i * 64) * K + k1, nA + i * 4096 + wv * 512);
    }

    short8 af[4][2], bf[2][2];
    // bf first (every MFMA needs it), then af m0-3
#pragma unroll
    for (int n = 0; n < 2; n++)
#pragma unroll
      for (int ks = 0; ks < 2; ks++)
        bf[n][ks] = *(const short8*)(lB + (wn + n * 16 + lc) * 64 + (((ks * 4 + quad) ^ sw) * 8));
#pragma unroll
    for (int m = 0; m < 4; m++)
#pragma unroll
      for (int ks = 0; ks < 2; ks++)
        af[m][ks] = *(const short8*)(bufA + (wm + m * 16 + lc) * 64 + (((ks * 4 + quad) ^ sw) * 8));
    __builtin_amdgcn_s_setprio(1);
#pragma unroll
    for (int m = 0; m < 4; m++)
#pragma unroll
      for (int n = 0; n < 2; n++)
#pragma unroll
        for (int ks = 0; ks < 2; ks++)
          acc[m][n] = __builtin_amdgcn_mfma_f32_16x16x32_bf16(af[m][ks], bf[n][ks], acc[m][n], 0, 0, 0);
    __builtin_amdgcn_s_setprio(0);
    BARRIER();   // all waves' bf (and af m0-3) reads consumed -> lB reusable

    // stage B(t+1) into the (now dead) single B buffer
    if (st) {
#pragma unroll
      for (int i = 0; i < 2; i++)
        GL16(gB + (size_t)(i * 64) * K + k1, lB + i * 4096 + wv * 512);
    }
    // af m4-7 (reuse regs); bufA parity not written until tile t+1's start
#pragma unroll
    for (int m = 0; m < 4; m++)
#pragma unroll
      for (int ks = 0; ks < 2; ks++)
        af[m][ks] = *(const short8*)(bufA + (wm + (m + 4) * 16 + lc) * 64 + (((ks * 4 + quad) ^ sw) * 8));
    __builtin_amdgcn_s_setprio(1);
#pragma unroll
    for (int m = 0; m < 4; m++)
#pragma unroll
      for (int n = 0; n < 2; n++)
#pragma unroll
        for (int ks = 0; ks < 2; ks++)
          acc[m + 4][n] = __builtin_amdgcn_mfma_f32_16x16x32_bf16(af[m][ks], bf[n][ks], acc[m + 4][n], 0, 0, 0);
    __builtin_amdgcn_s_setprio(0);
    asm volatile("s_waitcnt vmcnt(0)" ::: "memory");   // t+1 A and B landed
    BARRIER();                                         // visible to all waves
  }

  // ---- epilogue ----
  float bv[2];
#pragma unroll
  for (int j = 0; j < 2; j++) bv[j] = bias[n0 + wn + j * 16 + lc];
#pragma unroll
  for (int i = 0; i < 8; i++) {
#pragma unroll
    for (int j = 0; j < 2; j++) {
#pragma unroll
      for (int r = 0; r < 4; r++) {
        size_t idx = (size_t)(m0 + wm + i * 16 + quad * 4 + r) * N + (n0 + wn + j * 16 + lc);
        float v = acc[i][j][r] + bv[j];
        if (OUT_F32) ((float*)Cout)[idx] = v;
        else         ((unsigned short*)Cout)[idx] = f2bf(v);
      }
    }
  }
}

// ---- flash attention, paired q-tiles (j, 31-j), XCD-grouped blocks ----
#define LP_STRIDE 68   // pad: pf b128 reads land 2-way/bank (free)
__global__ __launch_bounds__(256, 4)
void k_flash(const unsigned short* __restrict__ qkv,
             const unsigned short* __restrict__ vt,
             unsigned short* __restrict__ y) {
  __shared__ unsigned short lK[64 * 64];
  __shared__ unsigned short lVT[64 * 64];
  __shared__ unsigned short lP[4][2][16 * LP_STRIDE];
  int tid = threadIdx.x, lane = tid & 63, wv = tid >> 6;
  int lc = lane & 15, quad = lane >> 4;
  int sw = lc & 7;

  // XCD grouping: dispatch heuristic XCD = raw%8.  Each XCD owns 8 bh values
  // with ALL 16 q-pair blocks of each -> K/V stay in that XCD's L2 (4 MB).
  int raw = blockIdx.y * 16 + blockIdx.x;      // 0..1023
  int bh  = (raw & 7) * 8 + ((raw >> 3) & 7);  // 0..63
  int j   = raw >> 6;                          // 0..15
  int b = bh >> 4, h = bh & 15;
  int qtA = j, qtB = 31 - j;
  int qrA = qtA * 64 + wv * 16;
  int qrB = qtB * 64 + wv * 16;

  short8 qfA[2], qfB[2];
  {
    const unsigned short* qp = qkv + (size_t)(b * 2048 + qrA + lc) * 3072 + h * 64 + quad * 8;
    qfA[0] = *(const short8*)qp;
    qfA[1] = *(const short8*)(qp + 32);
  }
  {
    const unsigned short* qp = qkv + (size_t)(b * 2048 + qrB + lc) * 3072 + h * 64 + quad * 8;
    qfB[0] = *(const short8*)qp;
    qfB[1] = *(const short8*)(qp + 32);
  }

  float rsA[4] = {0.f, 0.f, 0.f, 0.f}, rsB[4] = {0.f, 0.f, 0.f, 0.f};
  floatx4 oA[4], oB[4];
#pragma unroll
  for (int dt = 0; dt < 4; dt++) {
    oA[dt] = (floatx4){0.f, 0.f, 0.f, 0.f};
    oB[dt] = (floatx4){0.f, 0.f, 0.f, 0.f};
  }

  int srow = tid >> 3;
  int scol = ((tid & 7) ^ (srow & 7)) * 8;    // swizzled gather column
  const unsigned short* gK = qkv + (size_t)(b * 2048 + srow) * 3072 + 1024 + h * 64 + scol;
  const unsigned short* gV = vt + (size_t)(bh * 64 + srow) * 2048 + scol;

  const float SC2 = 0.18033688011f;   // (1/sqrt(64)) * log2(e)
  int nt = qtB + 1;

  for (int kv = 0; kv < nt; kv++) {
    int kv0 = kv * 64;
#pragma unroll
    for (int c = 0; c < 2; c++) {
      GL16(gK + (size_t)(kv0 + 32 * c) * 3072, lK + (32 * c + 8 * wv) * 64);
      GL16(gV + (size_t)(32 * c) * 2048 + kv0, lVT + (32 * c + 8 * wv) * 64);
    }
    __syncthreads();

    bool withA = (kv <= qtA);

    // ---- S = Q K^T for both q-tiles, sharing K fragments ----
    floatx4 sB[4], sA[4];
    __builtin_amdgcn_s_setprio(1);
#pragma unroll
    for (int n = 0; n < 4; n++) {
      short8 kf0 = *(const short8*)(lK + (n * 16 + lc) * 64 + ((quad ^ sw) * 8));
      short8 kf1 = *(const short8*)(lK + (n * 16 + lc) * 64 + (((4 + quad) ^ sw) * 8));
      floatx4 t = (floatx4){0.f, 0.f, 0.f, 0.f};
      t = __builtin_amdgcn_mfma_f32_16x16x32_bf16(qfB[0], kf0, t, 0, 0, 0);
      t = __builtin_amdgcn_mfma_f32_16x16x32_bf16(qfB[1], kf1, t, 0, 0, 0);
      sB[n] = t;
      if (withA) {
        floatx4 u = (floatx4){0.f, 0.f, 0.f, 0.f};
        u = __builtin_amdgcn_mfma_f32_16x16x32_bf16(qfA[0], kf0, u, 0, 0, 0);
        u = __builtin_amdgcn_mfma_f32_16x16x32_bf16(qfA[1], kf1, u, 0, 0, 0);
        sA[n] = u;
      }
    }
    __builtin_amdgcn_s_setprio(0);

    // ---- softmax numerators (no max subtraction), P -> LDS (trunc pack) ----
    {
      bool diag = (kv == qtB);
#pragma unroll
      for (int n = 0; n < 4; n++)
#pragma unroll
        for (int r = 0; r < 4; r++) {
          float arg = sB[n][r] * SC2;
          if (diag && (kv0 + n * 16 + lc > qrB + quad * 4 + r)) arg = -__builtin_inff();
          float p = __builtin_amdgcn_exp2f(arg);
          rsB[r] += p;
          lP[wv][0][(quad * 4 + r) * LP_STRIDE + n * 16 + lc] = f2bf_trunc(p);
        }
    }
    if (withA) {
      bool diag = (kv == qtA);
#pragma unroll
      for (int n = 0; n < 4; n++)
#pragma unroll
        for (int r = 0; r < 4; r++) {
          float arg = sA[n][r] * SC2;
          if (diag && (kv0 + n * 16 + lc > qrA + quad * 4 + r)) arg = -__builtin_inff();
          float p = __builtin_amdgcn_exp2f(arg);
          rsA[r] += p;
          lP[wv][1][(quad * 4 + r) * LP_STRIDE + n * 16 + lc] = f2bf_trunc(p);
        }
    }

    // ---- O += P @ V, sharing V fragments (same-wave lgkmcnt orders lP) ----
    __builtin_amdgcn_s_setprio(1);
#pragma unroll
    for (int s2 = 0; s2 < 2; s2++) {
      short8 pfB = *(const short8*)(&lP[wv][0][0] + lc * LP_STRIDE + s2 * 32 + quad * 8);
      short8 pfA;
      if (withA) pfA = *(const short8*)(&lP[wv][1][0] + lc * LP_STRIDE + s2 * 32 + quad * 8);
#pragma unroll
      for (int dt = 0; dt < 4; dt++) {
        short8 vf = *(const short8*)(lVT + (dt * 16 + lc) * 64 + (((s2 * 4 + quad) ^ sw) * 8));
        oB[dt] = __builtin_amdgcn_mfma_f32_16x16x32_bf16(pfB, vf, oB[dt], 0, 0, 0);
        if (withA) oA[dt] = __builtin_amdgcn_mfma_f32_16x16x32_bf16(pfA, vf, oA[dt], 0, 0, 0);
      }
    }
    __builtin_amdgcn_s_setprio(0);
    __syncthreads();   // protect lK/lVT before next stage
  }

  // ---- epilogue: one row-sum butterfly, normalize, store both tiles ----
#pragma unroll
  for (int off = 1; off < 16; off <<= 1)
#pragma unroll
    for (int r = 0; r < 4; r++) {
      rsA[r] += __shfl_xor(rsA[r], off);
      rsB[r] += __shfl_xor(rsB[r], off);
    }
#pragma unroll
  for (int r = 0; r < 4; r++) {
    float invA = 1.0f / rsA[r];
    float invB = 1.0f / rsB[r];
#pragma unroll
    for (int dt = 0; dt < 4; dt++) {
      size_t ia = (size_t)(b * 2048 + qrA + quad * 4 + r) * 1024 + h * 64 + dt * 16 + lc;
      size_t ib = (size_t)(b * 2048 + qrB + quad * 4 + r) * 1024 + h * 64 + dt * 16 + lc;
      y[ia] = f2bf(oA[dt][r] * invA);
      y[ib] = f2bf(oB[dt][r] * invB);
    }
  }
}

extern "C" void kernel_launch(void* const* d_in, const int* in_sizes, int n_in,
                              void* d_out, int out_size, void* d_ws, size_t ws_size,
                              hipStream_t stream) {
  const float* x      = (const float*)d_in[0];
  const float* W_attn = (const float*)d_in[1];
  const float* b_attn = (const float*)d_in[2];
  const float* W_proj = (const float*)d_in[3];
  const float* b_proj = (const float*)d_in[4];

  char* ws = (char*)d_ws;
  unsigned short* xb     = (unsigned short*)ws;                    // 16.8 MB (reused as y)
  unsigned short* wattnT = (unsigned short*)(ws + 16777216);       // 6.3 MB
  unsigned short* wprojT = (unsigned short*)(ws + 23068672);       // 2.1 MB
  unsigned short* qkv    = (unsigned short*)(ws + 25165824);       // 50.3 MB
  unsigned short* vt     = (unsigned short*)(ws + 75497472);       // 16.8 MB -> total 92.3 MB
  unsigned short* y      = xb;   // xb dead after QKV GEMM

  k_cvt<<<8192, 256, 0, stream>>>(x, xb, 8388608 / 4);
  k_tw<<<dim3(96, 32), dim3(32, 8), 0, stream>>>(W_attn, wattnT, 1024, 3072);
  k_tw<<<dim3(32, 32), dim3(32, 8), 0, stream>>>(W_proj, wprojT, 1024, 1024);
  // QKV GEMM: 256x128 tiles, grid 24x32 = 768 blocks, 2 blocks/CU
  k_gemm2<0><<<dim3(24, 32), 512, 0, stream>>>(xb, wattnT, b_attn, qkv, 8192, 3072, 1024);
  k_tv<<<dim3(64, 2, 64), dim3(32, 8), 0, stream>>>(qkv, vt);
  k_flash<<<dim3(16, 64), 256, 0, stream>>>(qkv, vt, y);
  // proj GEMM: 256x128 tiles, grid 8x32 = 256 blocks
  k_gemm2<1><<<dim3(8, 32), 512, 0, stream>>>(y, wprojT, b_proj, d_out, 8192, 1024, 1024);
}

// Round 8
// 250.686 us; speedup vs baseline: 1.1250x; 1.1250x over previous
//
#include <hip/hip_runtime.h>
#include <stdint.h>

// ---------------------------------------------------------------------------
// CausalSelfAttention: x[4,2048,1024] -> qkv -> flash attn -> proj
// Round 11: GEMM K-loop de-lockstepped.  R6 had 5 barriers/K-tile with
// ds_reads -> BARRIER -> MFMA (blocks compiler interleave + locksteps waves).
// R7 proved occupancy is NOT the limit (occ 19.5->30.5, MfmaUtil 27.8->22.5).
// New schedule (m97-proven shape): A AND B double-buffered; per K-tile:
// {issue t+1 gloads at top | all ds_reads + 48 MFMA in ONE barrier-free
// region | vmcnt(0) (issued a tile ago -> cheap) | ONE barrier}.
// Geometry kept from R6: NF=3 QKV 256x192, 512 blocks = 2 exact rounds;
// NF=2 proj 256x128, 256 blocks = 1 round.  LDS 112K/96K -> 1 blk/CU.
// Flash (XCD-grouped R8) unchanged.
// ---------------------------------------------------------------------------

typedef __attribute__((ext_vector_type(8))) short short8;   // 8 bf16 (4 VGPRs)
typedef __attribute__((ext_vector_type(4))) float floatx4;  // MFMA C/D frag

#define AS1C(p) ((const __attribute__((address_space(1))) void*)(p))
#define AS3(p)  ((__attribute__((address_space(3))) void*)(p))
#define GL16(src, dst) __builtin_amdgcn_global_load_lds(AS1C(src), AS3(dst), 16, 0, 0)
#define BARRIER() do { asm volatile("" ::: "memory"); __builtin_amdgcn_s_barrier(); asm volatile("" ::: "memory"); } while (0)

__device__ __forceinline__ unsigned short f2bf(float f) {
  unsigned int u = __builtin_bit_cast(unsigned int, f);
  u = (u + 0x7fffu + ((u >> 16) & 1u)) >> 16;   // RNE
  return (unsigned short)u;
}
__device__ __forceinline__ unsigned short f2bf_trunc(float f) {
  return (unsigned short)(__builtin_bit_cast(unsigned int, f) >> 16);
}

// ---- fp32 -> bf16 elementwise (x4 vectorized) ----
__global__ void k_cvt(const float* __restrict__ in, unsigned short* __restrict__ out, int n4) {
  int i = blockIdx.x * blockDim.x + threadIdx.x;
  if (i < n4) {
    float4 v = ((const float4*)in)[i];
    ushort4 o;
    o.x = f2bf(v.x); o.y = f2bf(v.y); o.z = f2bf(v.z); o.w = f2bf(v.w);
    ((ushort4*)out)[i] = o;
  }
}

// ---- transpose fp32 [K][N] -> bf16 [N][K] (weights) ----
__global__ void k_tw(const float* __restrict__ in, unsigned short* __restrict__ out, int K, int N) {
  __shared__ float t[32][33];
  int n0 = blockIdx.x * 32, k0 = blockIdx.y * 32;
  int tx = threadIdx.x, ty = threadIdx.y;
#pragma unroll
  for (int i = 0; i < 4; i++)
    t[ty + 8 * i][tx] = in[(size_t)(k0 + ty + 8 * i) * N + n0 + tx];
  __syncthreads();
#pragma unroll
  for (int i = 0; i < 4; i++)
    out[(size_t)(n0 + ty + 8 * i) * K + k0 + tx] = f2bf(t[tx][ty + 8 * i]);
}

// ---- transpose V slice of qkv (bf16) -> VT[bh][d][t] ----
__global__ void k_tv(const unsigned short* __restrict__ qkv, unsigned short* __restrict__ vt) {
  __shared__ unsigned short t[32][33];
  int t0 = blockIdx.x * 32;         // time tile
  int d0 = blockIdx.y * 32;         // head-dim tile (0 or 32)
  int bh = blockIdx.z;              // 0..63
  int b = bh >> 4, h = bh & 15;
  int tx = threadIdx.x, ty = threadIdx.y;
#pragma unroll
  for (int i = 0; i < 4; i++)
    t[ty + 8 * i][tx] = qkv[(size_t)(b * 2048 + t0 + ty + 8 * i) * 3072 + 2048 + h * 64 + d0 + tx];
  __syncthreads();
#pragma unroll
  for (int i = 0; i < 4; i++)
    vt[(size_t)(bh * 64 + d0 + ty + 8 * i) * 2048 + t0 + tx] = t[tx][ty + 8 * i];
}

// ---------------------------------------------------------------------------
// 256x(NF*64)-tile bf16 GEMM, C = A[M,K] @ Bt[N,K]^T + bias.
// 8 waves: wm=(wv>>2)*128, wn=(wv&3)*NF*16 -> per-wave 128x(NF*16), acc[8][NF].
// A dbuf (64K) + B dbuf (NF*32K/2): one barrier + one vmcnt per K-tile.
// Per K-tile t: issue A(t+1)+B(t+1) gloads into parity (t+1)&1 (that parity
// was last read in tile t-1; all waves passed t-1's end barrier -> no WAR);
// then bf + af(m0-3) reads, 24*NF/3 MFMA, af(m4-7) reads, MFMA -- one
// straight-line region, compiler interleaves via lgkmcnt; then vmcnt(0)
// (loads issued a full tile ago) + BARRIER (t+1 visible to all waves).
// ---------------------------------------------------------------------------
template <int OUT_F32, int NF>
__global__ __launch_bounds__(512, 2)
void k_gemm8(const unsigned short* __restrict__ A,
             const unsigned short* __restrict__ Bt,
             const float* __restrict__ bias,
             void* __restrict__ Cout, int M, int N, int K) {
  __shared__ unsigned short lA[2][256 * 64];        // 64 KiB
  __shared__ unsigned short lB[2][NF * 64 * 64];    // 48 (NF=3) / 32 (NF=2) KiB
  int tid = threadIdx.x;
  int lane = tid & 63, wv = tid >> 6;               // 8 waves
  int lc = lane & 15, quad = lane >> 4;
  int sw = lc & 7;

  // T1: XCD-aware block swizzle (nwg % 8 == 0 for both launches)
  unsigned nbx = gridDim.x;
  unsigned nwg = nbx * gridDim.y;
  unsigned flat = blockIdx.y * nbx + blockIdx.x;
  unsigned cpx = nwg >> 3;
  unsigned tile = (flat & 7u) * cpx + (flat >> 3);
  int n0 = (int)(tile % nbx) * (NF * 64);
  int m0 = (int)(tile / nbx) * 256;

  int wm = (wv >> 2) * 128;         // 0,128
  int wn = (wv & 3) * (NF * 16);    // 4 N-waves

  floatx4 acc[8][NF];
#pragma unroll
  for (int i = 0; i < 8; i++)
#pragma unroll
    for (int j = 0; j < NF; j++) acc[i][j] = (floatx4){0.f, 0.f, 0.f, 0.f};

  // staging geometry: one gload issue = 512 thr x 16B = 8 KiB = 64 rows
  int srow = tid >> 3;                          // 0..63
  int scol = ((tid & 7) ^ (srow & 7)) * 8;      // inverse-swizzled source chunk
  const unsigned short* gA = A + (size_t)(m0 + srow) * K + scol;
  const unsigned short* gB = Bt + (size_t)(n0 + srow) * K + scol;

  int NT = K >> 6;

  // prologue: stage K-tile 0 into parity 0; wait; barrier.
#pragma unroll
  for (int i = 0; i < 4; i++)  GL16(gA + (size_t)(i * 64) * K, &lA[0][i * 4096 + wv * 512]);
#pragma unroll
  for (int i = 0; i < NF; i++) GL16(gB + (size_t)(i * 64) * K, &lB[0][i * 4096 + wv * 512]);
  asm volatile("s_waitcnt vmcnt(0)" ::: "memory");
  __builtin_amdgcn_s_barrier();
  asm volatile("" ::: "memory");

  for (int t = 0; t < NT; ++t) {
    const unsigned short* bufA = lA[t & 1];
    const unsigned short* bufB = lB[t & 1];
    bool st = (t + 1) < NT;

    // issue next tile's staging FIRST (full-tile latency cover).
    if (st) {
      unsigned short* nA = lA[(t + 1) & 1];
      unsigned short* nB = lB[(t + 1) & 1];
      int k1 = (t + 1) << 6;
#pragma unroll
      for (int i = 0; i < 4; i++)
        GL16(gA + (size_t)(i * 64) * K + k1, nA + i * 4096 + wv * 512);
#pragma unroll
      for (int i = 0; i < NF; i++)
        GL16(gB + (size_t)(i * 64) * K + k1, nB + i * 4096 + wv * 512);
    }

    // ---- compute tile t: one barrier-free region ----
    short8 af[4][2], bf[NF][2];
#pragma unroll
    for (int n = 0; n < NF; n++)
#pragma unroll
      for (int ks = 0; ks < 2; ks++)
        bf[n][ks] = *(const short8*)(bufB + (wn + n * 16 + lc) * 64 + (((ks * 4 + quad) ^ sw) * 8));
#pragma unroll
    for (int m = 0; m < 4; m++)
#pragma unroll
      for (int ks = 0; ks < 2; ks++)
        af[m][ks] = *(const short8*)(bufA + (wm + m * 16 + lc) * 64 + (((ks * 4 + quad) ^ sw) * 8));
    __builtin_amdgcn_s_setprio(1);
#pragma unroll
    for (int m = 0; m < 4; m++)
#pragma unroll
      for (int n = 0; n < NF; n++)
#pragma unroll
        for (int ks = 0; ks < 2; ks++)
          acc[m][n] = __builtin_amdgcn_mfma_f32_16x16x32_bf16(af[m][ks], bf[n][ks], acc[m][n], 0, 0, 0);
    __builtin_amdgcn_s_setprio(0);
#pragma unroll
    for (int m = 0; m < 4; m++)
#pragma unroll
      for (int ks = 0; ks < 2; ks++)
        af[m][ks] = *(const short8*)(bufA + (wm + (m + 4) * 16 + lc) * 64 + (((ks * 4 + quad) ^ sw) * 8));
    __builtin_amdgcn_s_setprio(1);
#pragma unroll
    for (int m = 0; m < 4; m++)
#pragma unroll
      for (int n = 0; n < NF; n++)
#pragma unroll
        for (int ks = 0; ks < 2; ks++)
          acc[m + 4][n] = __builtin_amdgcn_mfma_f32_16x16x32_bf16(af[m][ks], bf[n][ks], acc[m + 4][n], 0, 0, 0);
    __builtin_amdgcn_s_setprio(0);

    // ---- tile boundary: t+1 landed (issued a full tile ago) + barrier ----
    if (st) {
      asm volatile("s_waitcnt vmcnt(0)" ::: "memory");
      BARRIER();
    }
  }

  // ---- epilogue ----
  float bv[NF];
#pragma unroll
  for (int j = 0; j < NF; j++) bv[j] = bias[n0 + wn + j * 16 + lc];
#pragma unroll
  for (int i = 0; i < 8; i++) {
#pragma unroll
    for (int j = 0; j < NF; j++) {
#pragma unroll
      for (int r = 0; r < 4; r++) {
        size_t idx = (size_t)(m0 + wm + i * 16 + quad * 4 + r) * N + (n0 + wn + j * 16 + lc);
        float v = acc[i][j][r] + bv[j];
        if (OUT_F32) ((float*)Cout)[idx] = v;
        else         ((unsigned short*)Cout)[idx] = f2bf(v);
      }
    }
  }
}

// ---- flash attention, paired q-tiles (j, 31-j), XCD-grouped blocks ----
#define LP_STRIDE 68   // pad: pf b128 reads land 2-way/bank (free)
__global__ __launch_bounds__(256, 4)
void k_flash(const unsigned short* __restrict__ qkv,
             const unsigned short* __restrict__ vt,
             unsigned short* __restrict__ y) {
  __shared__ unsigned short lK[64 * 64];
  __shared__ unsigned short lVT[64 * 64];
  __shared__ unsigned short lP[4][2][16 * LP_STRIDE];
  int tid = threadIdx.x, lane = tid & 63, wv = tid >> 6;
  int lc = lane & 15, quad = lane >> 4;
  int sw = lc & 7;

  // XCD grouping: dispatch heuristic XCD = raw%8.  Each XCD owns 8 bh values
  // with ALL 16 q-pair blocks of each -> K/V stay in that XCD's L2 (4 MB).
  int raw = blockIdx.y * 16 + blockIdx.x;      // 0..1023
  int bh  = (raw & 7) * 8 + ((raw >> 3) & 7);  // 0..63
  int j   = raw >> 6;                          // 0..15
  int b = bh >> 4, h = bh & 15;
  int qtA = j, qtB = 31 - j;
  int qrA = qtA * 64 + wv * 16;
  int qrB = qtB * 64 + wv * 16;

  short8 qfA[2], qfB[2];
  {
    const unsigned short* qp = qkv + (size_t)(b * 2048 + qrA + lc) * 3072 + h * 64 + quad * 8;
    qfA[0] = *(const short8*)qp;
    qfA[1] = *(const short8*)(qp + 32);
  }
  {
    const unsigned short* qp = qkv + (size_t)(b * 2048 + qrB + lc) * 3072 + h * 64 + quad * 8;
    qfB[0] = *(const short8*)qp;
    qfB[1] = *(const short8*)(qp + 32);
  }

  float rsA[4] = {0.f, 0.f, 0.f, 0.f}, rsB[4] = {0.f, 0.f, 0.f, 0.f};
  floatx4 oA[4], oB[4];
#pragma unroll
  for (int dt = 0; dt < 4; dt++) {
    oA[dt] = (floatx4){0.f, 0.f, 0.f, 0.f};
    oB[dt] = (floatx4){0.f, 0.f, 0.f, 0.f};
  }

  int srow = tid >> 3;
  int scol = ((tid & 7) ^ (srow & 7)) * 8;    // swizzled gather column
  const unsigned short* gK = qkv + (size_t)(b * 2048 + srow) * 3072 + 1024 + h * 64 + scol;
  const unsigned short* gV = vt + (size_t)(bh * 64 + srow) * 2048 + scol;

  const float SC2 = 0.18033688011f;   // (1/sqrt(64)) * log2(e)
  int nt = qtB + 1;

  for (int kv = 0; kv < nt; kv++) {
    int kv0 = kv * 64;
#pragma unroll
    for (int c = 0; c < 2; c++) {
      GL16(gK + (size_t)(kv0 + 32 * c) * 3072, lK + (32 * c + 8 * wv) * 64);
      GL16(gV + (size_t)(32 * c) * 2048 + kv0, lVT + (32 * c + 8 * wv) * 64);
    }
    __syncthreads();

    bool withA = (kv <= qtA);

    // ---- S = Q K^T for both q-tiles, sharing K fragments ----
    floatx4 sB[4], sA[4];
    __builtin_amdgcn_s_setprio(1);
#pragma unroll
    for (int n = 0; n < 4; n++) {
      short8 kf0 = *(const short8*)(lK + (n * 16 + lc) * 64 + ((quad ^ sw) * 8));
      short8 kf1 = *(const short8*)(lK + (n * 16 + lc) * 64 + (((4 + quad) ^ sw) * 8));
      floatx4 t = (floatx4){0.f, 0.f, 0.f, 0.f};
      t = __builtin_amdgcn_mfma_f32_16x16x32_bf16(qfB[0], kf0, t, 0, 0, 0);
      t = __builtin_amdgcn_mfma_f32_16x16x32_bf16(qfB[1], kf1, t, 0, 0, 0);
      sB[n] = t;
      if (withA) {
        floatx4 u = (floatx4){0.f, 0.f, 0.f, 0.f};
        u = __builtin_amdgcn_mfma_f32_16x16x32_bf16(qfA[0], kf0, u, 0, 0, 0);
        u = __builtin_amdgcn_mfma_f32_16x16x32_bf16(qfA[1], kf1, u, 0, 0, 0);
        sA[n] = u;
      }
    }
    __builtin_amdgcn_s_setprio(0);

    // ---- softmax numerators (no max subtraction), P -> LDS (trunc pack) ----
    {
      bool diag = (kv == qtB);
#pragma unroll
      for (int n = 0; n < 4; n++)
#pragma unroll
        for (int r = 0; r < 4; r++) {
          float arg = sB[n][r] * SC2;
          if (diag && (kv0 + n * 16 + lc > qrB + quad * 4 + r)) arg = -__builtin_inff();
          float p = __builtin_amdgcn_exp2f(arg);
          rsB[r] += p;
          lP[wv][0][(quad * 4 + r) * LP_STRIDE + n * 16 + lc] = f2bf_trunc(p);
        }
    }
    if (withA) {
      bool diag = (kv == qtA);
#pragma unroll
      for (int n = 0; n < 4; n++)
#pragma unroll
        for (int r = 0; r < 4; r++) {
          float arg = sA[n][r] * SC2;
          if (diag && (kv0 + n * 16 + lc > qrA + quad * 4 + r)) arg = -__builtin_inff();
          float p = __builtin_amdgcn_exp2f(arg);
          rsA[r] += p;
          lP[wv][1][(quad * 4 + r) * LP_STRIDE + n * 16 + lc] = f2bf_trunc(p);
        }
    }

    // ---- O += P @ V, sharing V fragments (same-wave lgkmcnt orders lP) ----
    __builtin_amdgcn_s_setprio(1);
#pragma unroll
    for (int s2 = 0; s2 < 2; s2++) {
      short8 pfB = *(const short8*)(&lP[wv][0][0] + lc * LP_STRIDE + s2 * 32 + quad * 8);
      short8 pfA;
      if (withA) pfA = *(const short8*)(&lP[wv][1][0] + lc * LP_STRIDE + s2 * 32 + quad * 8);
#pragma unroll
      for (int dt = 0; dt < 4; dt++) {
        short8 vf = *(const short8*)(lVT + (dt * 16 + lc) * 64 + (((s2 * 4 + quad) ^ sw) * 8));
        oB[dt] = __builtin_amdgcn_mfma_f32_16x16x32_bf16(pfB, vf, oB[dt], 0, 0, 0);
        if (withA) oA[dt] = __builtin_amdgcn_mfma_f32_16x16x32_bf16(pfA, vf, oA[dt], 0, 0, 0);
      }
    }
    __builtin_amdgcn_s_setprio(0);
    __syncthreads();   // protect lK/lVT before next stage
  }

  // ---- epilogue: one row-sum butterfly, normalize, store both tiles ----
#pragma unroll
  for (int off = 1; off < 16; off <<= 1)
#pragma unroll
    for (int r = 0; r < 4; r++) {
      rsA[r] += __shfl_xor(rsA[r], off);
      rsB[r] += __shfl_xor(rsB[r], off);
    }
#pragma unroll
  for (int r = 0; r < 4; r++) {
    float invA = 1.0f / rsA[r];
    float invB = 1.0f / rsB[r];
#pragma unroll
    for (int dt = 0; dt < 4; dt++) {
      size_t ia = (size_t)(b * 2048 + qrA + quad * 4 + r) * 1024 + h * 64 + dt * 16 + lc;
      size_t ib = (size_t)(b * 2048 + qrB + quad * 4 + r) * 1024 + h * 64 + dt * 16 + lc;
      y[ia] = f2bf(oA[dt][r] * invA);
      y[ib] = f2bf(oB[dt][r] * invB);
    }
  }
}

extern "C" void kernel_launch(void* const* d_in, const int* in_sizes, int n_in,
                              void* d_out, int out_size, void* d_ws, size_t ws_size,
                              hipStream_t stream) {
  const float* x      = (const float*)d_in[0];
  const float* W_attn = (const float*)d_in[1];
  const float* b_attn = (const float*)d_in[2];
  const float* W_proj = (const float*)d_in[3];
  const float* b_proj = (const float*)d_in[4];

  char* ws = (char*)d_ws;
  unsigned short* xb     = (unsigned short*)ws;                    // 16.8 MB (reused as y)
  unsigned short* wattnT = (unsigned short*)(ws + 16777216);       // 6.3 MB
  unsigned short* wprojT = (unsigned short*)(ws + 23068672);       // 2.1 MB
  unsigned short* qkv    = (unsigned short*)(ws + 25165824);       // 50.3 MB
  unsigned short* vt     = (unsigned short*)(ws + 75497472);       // 16.8 MB -> total 92.3 MB
  unsigned short* y      = xb;   // xb dead after QKV GEMM

  k_cvt<<<8192, 256, 0, stream>>>(x, xb, 8388608 / 4);
  k_tw<<<dim3(96, 32), dim3(32, 8), 0, stream>>>(W_attn, wattnT, 1024, 3072);
  k_tw<<<dim3(32, 32), dim3(32, 8), 0, stream>>>(W_proj, wprojT, 1024, 1024);
  // QKV GEMM: 256x192 tiles, grid 16x32 = 512 blocks = 2 exact rounds
  k_gemm8<0, 3><<<dim3(16, 32), 512, 0, stream>>>(xb, wattnT, b_attn, qkv, 8192, 3072, 1024);
  k_tv<<<dim3(64, 2, 64), dim3(32, 8), 0, stream>>>(qkv, vt);
  k_flash<<<dim3(16, 64), 256, 0, stream>>>(qkv, vt, y);
  // proj GEMM: 256x128 tiles, grid 8x32 = 256 blocks = 1 exact round
  k_gemm8<1, 2><<<dim3(8, 32), 512, 0, stream>>>(y, wprojT, b_proj, d_out, 8192, 1024, 1024);
}

// Round 9
// 245.332 us; speedup vs baseline: 1.1495x; 1.0218x over previous
//
#include <hip/hip_runtime.h>
#include <stdint.h>

// ---------------------------------------------------------------------------
// CausalSelfAttention: x[4,2048,1024] -> qkv -> flash attn -> proj
// Round 12: launch-count reduction + k_tv coalescing.  Accounting showed
// ~55-60 us unexplained across 6 kernel boundaries (~10 us each, the
// documented launch-overhead scale).  k_cvt + k_tw + k_tw fused into one
// flat-grid k_prep (7 -> 5 launches).  k_tv rewritten with 64-wide tiles so
// qkv reads / vt writes are full 128B lines (was 64B segments @ 6KB stride).
// GEMMs (R8 1-barrier dbuf schedule) and flash (XCD-grouped) unchanged.
// ---------------------------------------------------------------------------

typedef __attribute__((ext_vector_type(8))) short short8;   // 8 bf16 (4 VGPRs)
typedef __attribute__((ext_vector_type(4))) float floatx4;  // MFMA C/D frag

#define AS1C(p) ((const __attribute__((address_space(1))) void*)(p))
#define AS3(p)  ((__attribute__((address_space(3))) void*)(p))
#define GL16(src, dst) __builtin_amdgcn_global_load_lds(AS1C(src), AS3(dst), 16, 0, 0)
#define BARRIER() do { asm volatile("" ::: "memory"); __builtin_amdgcn_s_barrier(); asm volatile("" ::: "memory"); } while (0)

__device__ __forceinline__ unsigned short f2bf(float f) {
  unsigned int u = __builtin_bit_cast(unsigned int, f);
  u = (u + 0x7fffu + ((u >> 16) & 1u)) >> 16;   // RNE
  return (unsigned short)u;
}
__device__ __forceinline__ unsigned short f2bf_trunc(float f) {
  return (unsigned short)(__builtin_bit_cast(unsigned int, f) >> 16);
}

// ---------------------------------------------------------------------------
// Fused prep: [0,8192) cvt x->bf16; [8192,11264) tw W_attn; [11264,12288) tw
// W_proj.  All sub-tasks use 256 threads; tw uses tx=tid&31, ty=tid>>5.
// ---------------------------------------------------------------------------
__global__ __launch_bounds__(256)
void k_prep(const float* __restrict__ x, unsigned short* __restrict__ xb,
            const float* __restrict__ Wa, unsigned short* __restrict__ WaT,
            const float* __restrict__ Wp, unsigned short* __restrict__ WpT) {
  __shared__ float t[32][33];
  int bid = blockIdx.x;
  int tid = threadIdx.x;
  if (bid < 8192) {
    int i = bid * 256 + tid;           // n4 = 2097152 = 8192*256 exactly
    float4 v = ((const float4*)x)[i];
    ushort4 o;
    o.x = f2bf(v.x); o.y = f2bf(v.y); o.z = f2bf(v.z); o.w = f2bf(v.w);
    ((ushort4*)xb)[i] = o;
    return;
  }
  const float* in; unsigned short* out; int K = 1024, N, n0, k0;
  if (bid < 11264) {                   // W_attn: 96x32 tiles of [1024][3072]
    int b2 = bid - 8192;
    in = Wa; out = WaT; N = 3072;
    n0 = (b2 % 96) * 32; k0 = (b2 / 96) * 32;
  } else {                             // W_proj: 32x32 tiles of [1024][1024]
    int b2 = bid - 11264;
    in = Wp; out = WpT; N = 1024;
    n0 = (b2 % 32) * 32; k0 = (b2 / 32) * 32;
  }
  int tx = tid & 31, ty = tid >> 5;
#pragma unroll
  for (int i = 0; i < 4; i++)
    t[ty + 8 * i][tx] = in[(size_t)(k0 + ty + 8 * i) * N + n0 + tx];
  __syncthreads();
#pragma unroll
  for (int i = 0; i < 4; i++)
    out[(size_t)(n0 + ty + 8 * i) * K + k0 + tx] = f2bf(t[tx][ty + 8 * i]);
}

// ---- transpose V slice of qkv (bf16) -> VT[bh][d][t], 64-wide tiles ----
// Reads and writes are full 128B contiguous lines; LDS [64][65] transpose
// read is 2-way bank-aliased (free, m136).
__global__ __launch_bounds__(256)
void k_tv(const unsigned short* __restrict__ qkv, unsigned short* __restrict__ vt) {
  __shared__ unsigned short t[64][65];
  int t0 = blockIdx.x * 64;         // time tile
  int bh = blockIdx.y;              // 0..63
  int b = bh >> 4, h = bh & 15;
  int tx = threadIdx.x & 63, ty = threadIdx.x >> 6;   // 64 x 4
#pragma unroll
  for (int i = 0; i < 16; i++)
    t[ty + 4 * i][tx] = qkv[(size_t)(b * 2048 + t0 + ty + 4 * i) * 3072 + 2048 + h * 64 + tx];
  __syncthreads();
#pragma unroll
  for (int i = 0; i < 16; i++)
    vt[(size_t)(bh * 64 + ty + 4 * i) * 2048 + t0 + tx] = t[tx][ty + 4 * i];
}

// ---------------------------------------------------------------------------
// 256x(NF*64)-tile bf16 GEMM, C = A[M,K] @ Bt[N,K]^T + bias.
// A+B double-buffered; one barrier + one vmcnt per K-tile (R8 schedule).
// ---------------------------------------------------------------------------
template <int OUT_F32, int NF>
__global__ __launch_bounds__(512, 2)
void k_gemm8(const unsigned short* __restrict__ A,
             const unsigned short* __restrict__ Bt,
             const float* __restrict__ bias,
             void* __restrict__ Cout, int M, int N, int K) {
  __shared__ unsigned short lA[2][256 * 64];        // 64 KiB
  __shared__ unsigned short lB[2][NF * 64 * 64];    // 48 (NF=3) / 32 (NF=2) KiB
  int tid = threadIdx.x;
  int lane = tid & 63, wv = tid >> 6;               // 8 waves
  int lc = lane & 15, quad = lane >> 4;
  int sw = lc & 7;

  // T1: XCD-aware block swizzle (nwg % 8 == 0 for both launches)
  unsigned nbx = gridDim.x;
  unsigned nwg = nbx * gridDim.y;
  unsigned flat = blockIdx.y * nbx + blockIdx.x;
  unsigned cpx = nwg >> 3;
  unsigned tile = (flat & 7u) * cpx + (flat >> 3);
  int n0 = (int)(tile % nbx) * (NF * 64);
  int m0 = (int)(tile / nbx) * 256;

  int wm = (wv >> 2) * 128;         // 0,128
  int wn = (wv & 3) * (NF * 16);    // 4 N-waves

  floatx4 acc[8][NF];
#pragma unroll
  for (int i = 0; i < 8; i++)
#pragma unroll
    for (int j = 0; j < NF; j++) acc[i][j] = (floatx4){0.f, 0.f, 0.f, 0.f};

  // staging geometry: one gload issue = 512 thr x 16B = 8 KiB = 64 rows
  int srow = tid >> 3;                          // 0..63
  int scol = ((tid & 7) ^ (srow & 7)) * 8;      // inverse-swizzled source chunk
  const unsigned short* gA = A + (size_t)(m0 + srow) * K + scol;
  const unsigned short* gB = Bt + (size_t)(n0 + srow) * K + scol;

  int NT = K >> 6;

  // prologue: stage K-tile 0 into parity 0; wait; barrier.
#pragma unroll
  for (int i = 0; i < 4; i++)  GL16(gA + (size_t)(i * 64) * K, &lA[0][i * 4096 + wv * 512]);
#pragma unroll
  for (int i = 0; i < NF; i++) GL16(gB + (size_t)(i * 64) * K, &lB[0][i * 4096 + wv * 512]);
  asm volatile("s_waitcnt vmcnt(0)" ::: "memory");
  __builtin_amdgcn_s_barrier();
  asm volatile("" ::: "memory");

  for (int t = 0; t < NT; ++t) {
    const unsigned short* bufA = lA[t & 1];
    const unsigned short* bufB = lB[t & 1];
    bool st = (t + 1) < NT;

    // issue next tile's staging FIRST (full-tile latency cover).
    if (st) {
      unsigned short* nA = lA[(t + 1) & 1];
      unsigned short* nB = lB[(t + 1) & 1];
      int k1 = (t + 1) << 6;
#pragma unroll
      for (int i = 0; i < 4; i++)
        GL16(gA + (size_t)(i * 64) * K + k1, nA + i * 4096 + wv * 512);
#pragma unroll
      for (int i = 0; i < NF; i++)
        GL16(gB + (size_t)(i * 64) * K + k1, nB + i * 4096 + wv * 512);
    }

    // ---- compute tile t: one barrier-free region ----
    short8 af[4][2], bf[NF][2];
#pragma unroll
    for (int n = 0; n < NF; n++)
#pragma unroll
      for (int ks = 0; ks < 2; ks++)
        bf[n][ks] = *(const short8*)(bufB + (wn + n * 16 + lc) * 64 + (((ks * 4 + quad) ^ sw) * 8));
#pragma unroll
    for (int m = 0; m < 4; m++)
#pragma unroll
      for (int ks = 0; ks < 2; ks++)
        af[m][ks] = *(const short8*)(bufA + (wm + m * 16 + lc) * 64 + (((ks * 4 + quad) ^ sw) * 8));
    __builtin_amdgcn_s_setprio(1);
#pragma unroll
    for (int m = 0; m < 4; m++)
#pragma unroll
      for (int n = 0; n < NF; n++)
#pragma unroll
        for (int ks = 0; ks < 2; ks++)
          acc[m][n] = __builtin_amdgcn_mfma_f32_16x16x32_bf16(af[m][ks], bf[n][ks], acc[m][n], 0, 0, 0);
    __builtin_amdgcn_s_setprio(0);
#pragma unroll
    for (int m = 0; m < 4; m++)
#pragma unroll
      for (int ks = 0; ks < 2; ks++)
        af[m][ks] = *(const short8*)(bufA + (wm + (m + 4) * 16 + lc) * 64 + (((ks * 4 + quad) ^ sw) * 8));
    __builtin_amdgcn_s_setprio(1);
#pragma unroll
    for (int m = 0; m < 4; m++)
#pragma unroll
      for (int n = 0; n < NF; n++)
#pragma unroll
        for (int ks = 0; ks < 2; ks++)
          acc[m + 4][n] = __builtin_amdgcn_mfma_f32_16x16x32_bf16(af[m][ks], bf[n][ks], acc[m + 4][n], 0, 0, 0);
    __builtin_amdgcn_s_setprio(0);

    // ---- tile boundary: t+1 landed (issued a full tile ago) + barrier ----
    if (st) {
      asm volatile("s_waitcnt vmcnt(0)" ::: "memory");
      BARRIER();
    }
  }

  // ---- epilogue ----
  float bv[NF];
#pragma unroll
  for (int j = 0; j < NF; j++) bv[j] = bias[n0 + wn + j * 16 + lc];
#pragma unroll
  for (int i = 0; i < 8; i++) {
#pragma unroll
    for (int j = 0; j < NF; j++) {
#pragma unroll
      for (int r = 0; r < 4; r++) {
        size_t idx = (size_t)(m0 + wm + i * 16 + quad * 4 + r) * N + (n0 + wn + j * 16 + lc);
        float v = acc[i][j][r] + bv[j];
        if (OUT_F32) ((float*)Cout)[idx] = v;
        else         ((unsigned short*)Cout)[idx] = f2bf(v);
      }
    }
  }
}

// ---- flash attention, paired q-tiles (j, 31-j), XCD-grouped blocks ----
#define LP_STRIDE 68   // pad: pf b128 reads land 2-way/bank (free)
__global__ __launch_bounds__(256, 4)
void k_flash(const unsigned short* __restrict__ qkv,
             const unsigned short* __restrict__ vt,
             unsigned short* __restrict__ y) {
  __shared__ unsigned short lK[64 * 64];
  __shared__ unsigned short lVT[64 * 64];
  __shared__ unsigned short lP[4][2][16 * LP_STRIDE];
  int tid = threadIdx.x, lane = tid & 63, wv = tid >> 6;
  int lc = lane & 15, quad = lane >> 4;
  int sw = lc & 7;

  // XCD grouping: dispatch heuristic XCD = raw%8.  Each XCD owns 8 bh values
  // with ALL 16 q-pair blocks of each -> K/V stay in that XCD's L2 (4 MB).
  int raw = blockIdx.y * 16 + blockIdx.x;      // 0..1023
  int bh  = (raw & 7) * 8 + ((raw >> 3) & 7);  // 0..63
  int j   = raw >> 6;                          // 0..15
  int b = bh >> 4, h = bh & 15;
  int qtA = j, qtB = 31 - j;
  int qrA = qtA * 64 + wv * 16;
  int qrB = qtB * 64 + wv * 16;

  short8 qfA[2], qfB[2];
  {
    const unsigned short* qp = qkv + (size_t)(b * 2048 + qrA + lc) * 3072 + h * 64 + quad * 8;
    qfA[0] = *(const short8*)qp;
    qfA[1] = *(const short8*)(qp + 32);
  }
  {
    const unsigned short* qp = qkv + (size_t)(b * 2048 + qrB + lc) * 3072 + h * 64 + quad * 8;
    qfB[0] = *(const short8*)qp;
    qfB[1] = *(const short8*)(qp + 32);
  }

  float rsA[4] = {0.f, 0.f, 0.f, 0.f}, rsB[4] = {0.f, 0.f, 0.f, 0.f};
  floatx4 oA[4], oB[4];
#pragma unroll
  for (int dt = 0; dt < 4; dt++) {
    oA[dt] = (floatx4){0.f, 0.f, 0.f, 0.f};
    oB[dt] = (floatx4){0.f, 0.f, 0.f, 0.f};
  }

  int srow = tid >> 3;
  int scol = ((tid & 7) ^ (srow & 7)) * 8;    // swizzled gather column
  const unsigned short* gK = qkv + (size_t)(b * 2048 + srow) * 3072 + 1024 + h * 64 + scol;
  const unsigned short* gV = vt + (size_t)(bh * 64 + srow) * 2048 + scol;

  const float SC2 = 0.18033688011f;   // (1/sqrt(64)) * log2(e)
  int nt = qtB + 1;

  for (int kv = 0; kv < nt; kv++) {
    int kv0 = kv * 64;
#pragma unroll
    for (int c = 0; c < 2; c++) {
      GL16(gK + (size_t)(kv0 + 32 * c) * 3072, lK + (32 * c + 8 * wv) * 64);
      GL16(gV + (size_t)(32 * c) * 2048 + kv0, lVT + (32 * c + 8 * wv) * 64);
    }
    __syncthreads();

    bool withA = (kv <= qtA);

    // ---- S = Q K^T for both q-tiles, sharing K fragments ----
    floatx4 sB[4], sA[4];
    __builtin_amdgcn_s_setprio(1);
#pragma unroll
    for (int n = 0; n < 4; n++) {
      short8 kf0 = *(const short8*)(lK + (n * 16 + lc) * 64 + ((quad ^ sw) * 8));
      short8 kf1 = *(const short8*)(lK + (n * 16 + lc) * 64 + (((4 + quad) ^ sw) * 8));
      floatx4 t = (floatx4){0.f, 0.f, 0.f, 0.f};
      t = __builtin_amdgcn_mfma_f32_16x16x32_bf16(qfB[0], kf0, t, 0, 0, 0);
      t = __builtin_amdgcn_mfma_f32_16x16x32_bf16(qfB[1], kf1, t, 0, 0, 0);
      sB[n] = t;
      if (withA) {
        floatx4 u = (floatx4){0.f, 0.f, 0.f, 0.f};
        u = __builtin_amdgcn_mfma_f32_16x16x32_bf16(qfA[0], kf0, u, 0, 0, 0);
        u = __builtin_amdgcn_mfma_f32_16x16x32_bf16(qfA[1], kf1, u, 0, 0, 0);
        sA[n] = u;
      }
    }
    __builtin_amdgcn_s_setprio(0);

    // ---- softmax numerators (no max subtraction), P -> LDS (trunc pack) ----
    {
      bool diag = (kv == qtB);
#pragma unroll
      for (int n = 0; n < 4; n++)
#pragma unroll
        for (int r = 0; r < 4; r++) {
          float arg = sB[n][r] * SC2;
          if (diag && (kv0 + n * 16 + lc > qrB + quad * 4 + r)) arg = -__builtin_inff();
          float p = __builtin_amdgcn_exp2f(arg);
          rsB[r] += p;
          lP[wv][0][(quad * 4 + r) * LP_STRIDE + n * 16 + lc] = f2bf_trunc(p);
        }
    }
    if (withA) {
      bool diag = (kv == qtA);
#pragma unroll
      for (int n = 0; n < 4; n++)
#pragma unroll
        for (int r = 0; r < 4; r++) {
          float arg = sA[n][r] * SC2;
          if (diag && (kv0 + n * 16 + lc > qrA + quad * 4 + r)) arg = -__builtin_inff();
          float p = __builtin_amdgcn_exp2f(arg);
          rsA[r] += p;
          lP[wv][1][(quad * 4 + r) * LP_STRIDE + n * 16 + lc] = f2bf_trunc(p);
        }
    }

    // ---- O += P @ V, sharing V fragments (same-wave lgkmcnt orders lP) ----
    __builtin_amdgcn_s_setprio(1);
#pragma unroll
    for (int s2 = 0; s2 < 2; s2++) {
      short8 pfB = *(const short8*)(&lP[wv][0][0] + lc * LP_STRIDE + s2 * 32 + quad * 8);
      short8 pfA;
      if (withA) pfA = *(const short8*)(&lP[wv][1][0] + lc * LP_STRIDE + s2 * 32 + quad * 8);
#pragma unroll
      for (int dt = 0; dt < 4; dt++) {
        short8 vf = *(const short8*)(lVT + (dt * 16 + lc) * 64 + (((s2 * 4 + quad) ^ sw) * 8));
        oB[dt] = __builtin_amdgcn_mfma_f32_16x16x32_bf16(pfB, vf, oB[dt], 0, 0, 0);
        if (withA) oA[dt] = __builtin_amdgcn_mfma_f32_16x16x32_bf16(pfA, vf, oA[dt], 0, 0, 0);
      }
    }
    __builtin_amdgcn_s_setprio(0);
    __syncthreads();   // protect lK/lVT before next stage
  }

  // ---- epilogue: one row-sum butterfly, normalize, store both tiles ----
#pragma unroll
  for (int off = 1; off < 16; off <<= 1)
#pragma unroll
    for (int r = 0; r < 4; r++) {
      rsA[r] += __shfl_xor(rsA[r], off);
      rsB[r] += __shfl_xor(rsB[r], off);
    }
#pragma unroll
  for (int r = 0; r < 4; r++) {
    float invA = 1.0f / rsA[r];
    float invB = 1.0f / rsB[r];
#pragma unroll
    for (int dt = 0; dt < 4; dt++) {
      size_t ia = (size_t)(b * 2048 + qrA + quad * 4 + r) * 1024 + h * 64 + dt * 16 + lc;
      size_t ib = (size_t)(b * 2048 + qrB + quad * 4 + r) * 1024 + h * 64 + dt * 16 + lc;
      y[ia] = f2bf(oA[dt][r] * invA);
      y[ib] = f2bf(oB[dt][r] * invB);
    }
  }
}

extern "C" void kernel_launch(void* const* d_in, const int* in_sizes, int n_in,
                              void* d_out, int out_size, void* d_ws, size_t ws_size,
                              hipStream_t stream) {
  const float* x      = (const float*)d_in[0];
  const float* W_attn = (const float*)d_in[1];
  const float* b_attn = (const float*)d_in[2];
  const float* W_proj = (const float*)d_in[3];
  const float* b_proj = (const float*)d_in[4];

  char* ws = (char*)d_ws;
  unsigned short* xb     = (unsigned short*)ws;                    // 16.8 MB (reused as y)
  unsigned short* wattnT = (unsigned short*)(ws + 16777216);       // 6.3 MB
  unsigned short* wprojT = (unsigned short*)(ws + 23068672);       // 2.1 MB
  unsigned short* qkv    = (unsigned short*)(ws + 25165824);       // 50.3 MB
  unsigned short* vt     = (unsigned short*)(ws + 75497472);       // 16.8 MB -> total 92.3 MB
  unsigned short* y      = xb;   // xb dead after QKV GEMM

  // fused prep: cvt (8192 blocks) + tw W_attn (3072) + tw W_proj (1024)
  k_prep<<<12288, 256, 0, stream>>>(x, xb, W_attn, wattnT, W_proj, wprojT);
  // QKV GEMM: 256x192 tiles, grid 16x32 = 512 blocks = 2 exact rounds
  k_gemm8<0, 3><<<dim3(16, 32), 512, 0, stream>>>(xb, wattnT, b_attn, qkv, 8192, 3072, 1024);
  // V transpose: 64-wide tiles, fully coalesced
  k_tv<<<dim3(32, 64), 256, 0, stream>>>(qkv, vt);
  k_flash<<<dim3(16, 64), 256, 0, stream>>>(qkv, vt, y);
  // proj GEMM: 256x128 tiles, grid 8x32 = 256 blocks = 1 exact round
  k_gemm8<1, 2><<<dim3(8, 32), 512, 0, stream>>>(y, wprojT, b_proj, d_out, 8192, 1024, 1024);
}